// Round 9
// baseline (643.267 us; speedup 1.0000x reference)
//
#include <hip/hip_runtime.h>

#define T_TOK 2048
#define HID   2048
#define INTER 768
#define NE    32
#define NSLOT 8192   // T_TOK * TOP_K
#define MAXT  96     // max (expert, mt) tiles at BM=128

typedef short bf16x8 __attribute__((ext_vector_type(8)));
typedef float f32x4  __attribute__((ext_vector_type(4)));

#if defined(__has_builtin)
#  if __has_builtin(__builtin_amdgcn_global_load_lds)
#    define HAS_GLDS 1
#  endif
#endif
#ifndef HAS_GLDS
#  define HAS_GLDS 0
#endif

__device__ __forceinline__ unsigned short f2b(float f){
  unsigned u = __builtin_bit_cast(unsigned, f);
  u += 0x7fffu + ((u >> 16) & 1u);      // RNE
  return (unsigned short)(u >> 16);
}
__device__ __forceinline__ unsigned pk2(float a, float b){
  return (unsigned)f2b(a) | ((unsigned)f2b(b) << 16);
}
__device__ __forceinline__ float b2f(unsigned short u){
  unsigned x = ((unsigned)u) << 16;
  return __builtin_bit_cast(float, x);
}

__device__ __forceinline__ void stageA16(const ushort* gsrc, ushort* ldst){
#if HAS_GLDS
  __builtin_amdgcn_global_load_lds(
      (const __attribute__((address_space(1))) unsigned int*)gsrc,
      (__attribute__((address_space(3))) unsigned int*)ldst, 16, 0, 0);
#else
  *(uint4*)ldst = *(const uint4*)gsrc;
#endif
}

// B LDS chunk swizzle key: col-major [col][k], 64B per col (BK=32 bf16),
// 16B k-chunk Q stored at Q ^ HB(c). HB uses c>>2 bits so write banks
// spread across the full lane index (col*64B stride cancels lane>>2 else).
__device__ __forceinline__ int HB(int c){ return ((c >> 2) ^ (c >> 4)) & 3; }

// ---------------- workspace layout (bytes) ----------------
#define XB_OFF    0ul           // bf16 x  [2048][2048]  = 8388608
#define GBUF_OFF  8388608ul     // bf16 g, then h in-place [8192][768] = 12582912
#define TKW_OFF   20971520ul    // f32 topk_w [2048][4]
#define TKI_OFF   21004288ul
#define ROWS_OFF  21037056ul
#define WTS_OFF   21069824ul
#define OFFS_OFF  21102592ul
#define LOGIT_OFF 21102848ul    // zeroed
#define CNT_OFF   21364992ul    // zeroed
#define FILL_OFF  21365120ul    // zeroed
#define TLIST_OFF 21365248ul
#define UBUF_OFF  21365760ul    // bf16 u [8192][768] = 12582912 (ends ~34 MB)
#define ZERO_OFF  21102848ul
#define ZERO_SZ   (262144ul + 128ul + 128ul)

// ---------------- x fp32 -> bf16 ----------------
__global__ void convert_x_kernel(const float* __restrict__ x, ushort* __restrict__ xb){
  int i = (blockIdx.x * 256 + threadIdx.x) * 8;
  float4 a = *(const float4*)(x + i);
  float4 b = *(const float4*)(x + i + 4);
  uint4 o;
  o.x = pk2(a.x, a.y);
  o.y = pk2(a.z, a.w);
  o.z = pk2(b.x, b.y);
  o.w = pk2(b.z, b.w);
  *(uint4*)(xb + i) = o;
}

// ---------------- router logits (fp32 GEMM, split-K atomic) ----------------
__global__ void router_gemm(const float* __restrict__ x, const float* __restrict__ wr,
                            float* __restrict__ logits){
  const int tt = blockIdx.x;
  const int kb = blockIdx.y;
  __shared__ float xs[64 * 64];
  __shared__ float wsm[64 * 32];
  const int tid = threadIdx.x;
  const int r = tid >> 5, e = tid & 31;
  float acc[8];
#pragma unroll
  for (int i = 0; i < 8; i++) acc[i] = 0.0f;

  for (int sub = 0; sub < 4; ++sub){
    const int k0 = kb * 256 + sub * 64;
    __syncthreads();
#pragma unroll
    for (int j = 0; j < 4; j++){
      int f4 = tid + j * 256;
      int row = f4 >> 4, c4 = f4 & 15;
      float4 v = *(const float4*)(x + (size_t)(tt * 64 + row) * HID + k0 + c4 * 4);
      *(float4*)(xs + row * 64 + c4 * 4) = v;
    }
#pragma unroll
    for (int j = 0; j < 2; j++){
      int f4 = tid + j * 256;
      int row = f4 >> 3, c4 = f4 & 7;
      float4 v = *(const float4*)(wr + (size_t)(k0 + row) * NE + c4 * 4);
      *(float4*)(wsm + row * NE + c4 * 4) = v;
    }
    __syncthreads();
    for (int kk = 0; kk < 64; kk++){
      float wv = wsm[kk * NE + e];
#pragma unroll
      for (int i = 0; i < 8; i++) acc[i] += xs[(r + i * 8) * 64 + kk] * wv;
    }
  }
#pragma unroll
  for (int i = 0; i < 8; i++)
    atomicAdd(&logits[(size_t)(tt * 64 + r + i * 8) * NE + e], acc[i]);
}

// ---------------- softmax + top-4 + renorm + counts ----------------
__global__ void topk_kernel(const float* __restrict__ logits, float* __restrict__ topk_w,
                            int* __restrict__ topk_i, int* __restrict__ counts){
  int t = blockIdx.x * blockDim.x + threadIdx.x;
  if (t >= T_TOK) return;
  float l[32];
  const float4* lp = (const float4*)(logits + (size_t)t * NE);
#pragma unroll
  for (int i = 0; i < 8; i++){
    float4 v = lp[i];
    l[i*4+0] = v.x; l[i*4+1] = v.y; l[i*4+2] = v.z; l[i*4+3] = v.w;
  }
  float m = l[0];
#pragma unroll
  for (int i = 1; i < 32; i++) m = fmaxf(m, l[i]);
#pragma unroll
  for (int i = 0; i < 32; i++) l[i] = __expf(l[i] - m);
  float wsel[4]; int isel[4];
#pragma unroll
  for (int k = 0; k < 4; k++){
    float best = l[0]; int bi = 0;
#pragma unroll
    for (int i = 1; i < 32; i++){ if (l[i] > best){ best = l[i]; bi = i; } }
    wsel[k] = best; isel[k] = bi; l[bi] = -1.0f;
  }
  float s4 = wsel[0] + wsel[1] + wsel[2] + wsel[3];
  float inv = 1.0f / s4;
#pragma unroll
  for (int k = 0; k < 4; k++){
    topk_w[t * 4 + k] = wsel[k] * inv;
    topk_i[t * 4 + k] = isel[k];
    atomicAdd(&counts[isel[k]], 1);
  }
}

__global__ void prefix_kernel(const int* __restrict__ counts, int* __restrict__ offsets,
                              int* __restrict__ tlist){
  if (threadIdx.x == 0){
    int a = 0; offsets[0] = 0; int nt_ = 0;
    for (int e = 0; e < NE; e++){
      int c = counts[e];
      for (int m = 0; m * 128 < c && nt_ < MAXT; m++) tlist[nt_++] = e | (m << 16);
      a += c; offsets[e + 1] = a;
    }
    for (; nt_ < MAXT; nt_++) tlist[nt_] = -1;
  }
}

__global__ void scatter_kernel(const int* __restrict__ topk_i, const float* __restrict__ topk_w,
                               const int* __restrict__ offsets, int* __restrict__ fill,
                               int* __restrict__ rows, float* __restrict__ wts){
  int gid = blockIdx.x * 256 + threadIdx.x;
  int t = gid >> 2;
  int e = topk_i[gid];
  int pos = atomicAdd(&fill[e], 1);
  int s = offsets[e] + pos;
  rows[s] = t;
  wts[s] = topk_w[gid];
}

// ---------------- gate/up GEMM (split matrices) ----------------
// BM=128, BN=128, BK=32, 512 thr (8 waves, 2m x 4n, 8 MFMA/step/wave).
// grid x = 16 (12 active: mat = x&1, nt = x>>1) -> ~792 active blocks
// (~3/CU) and mt-pairs at id-distance 16 = same XCD -> B panel L2 reuse.
// B: wave owns 4 k-rows; lane loads 2x float4 (rows R,R+1; 512B coalesced
// segments); packs k-pairs, writes 4x b32 with chunk-XOR HB(c) + col
// reorder i^(l&3) -> ~2-way banks. A via global_load_lds (src pre-swizzle).
#define NT_GU 64
#define GUV_STRIDE 8192   // ushorts per buffer: A 4096 | B 4096
__global__ __launch_bounds__(512) void guv_kernel(
    const ushort* __restrict__ xb, const float* __restrict__ wg,
    const float* __restrict__ wu, const int* __restrict__ rows,
    const int* __restrict__ counts, const int* __restrict__ offsets,
    const int* __restrict__ tlist, ushort* __restrict__ gbuf,
    ushort* __restrict__ ubuf)
{
  const int w = tlist[blockIdx.y];
  if (w < 0) return;
  const int x = blockIdx.x;
  if (x >= 12) return;
  const int e = w & 0xffff, mt = w >> 16;
  const int mat = x & 1, nt = x >> 1;   // nt 0..5
  const int cnt = counts[e], off = offsets[e];
  const int n0 = nt * 128;

  __shared__ __align__(16) ushort lds[2 * GUV_STRIDE];  // 32 KB

  const int tid = threadIdx.x;
  const int lane = tid & 63, wv = tid >> 6;

  // A staging: row ar, stored chunk tid&3 holds logical chunk (tid&3)^(ar&3)
  const int ar = tid >> 2;
  const int aq = (tid & 3) ^ (ar & 3);
  const int srow = mt * 128 + ar;
  const int tokA = rows[off + (srow < cnt ? srow : 0)];
  const ushort* agp = xb + (size_t)tokA * HID + aq * 8;

  // B staging
  const float* wsel = mat ? wu : wg;
  const int bl = lane & 31;                 // col-quad index (cols 4*bl..+3)
  const int brow = 4 * wv + 2 * (lane >> 5);
  const float* bgp = wsel + (size_t)e * (HID * INTER) + (size_t)brow * INTER + n0 + bl * 4;
  const int Qc = wv >> 1;                       // 16B chunk index of thread's k-pair
  const int wrd = (2 * wv + (lane >> 5)) & 3;   // 4B word within chunk

  // compute roles: 2m x 4n
  const int wm = wv >> 2, wn = wv & 3;
  const int fr = lane & 15, ko = lane >> 4;
  int aoff[4], boff[2];
#pragma unroll
  for (int mf = 0; mf < 4; mf++){
    int r = wm * 64 + mf * 16 + fr;
    aoff[mf] = r * 32 + ((ko ^ (r & 3)) << 3);
  }
#pragma unroll
  for (int nf = 0; nf < 2; nf++){
    int c = wn * 32 + nf * 16 + fr;
    boff[nf] = c * 32 + ((ko ^ HB(c)) << 3);
  }

  f32x4 acc[4][2];
#pragma unroll
  for (int i = 0; i < 4; i++)
#pragma unroll
    for (int j = 0; j < 2; j++) acc[i][j] = (f32x4)(0.0f);

  float4 br0, br1;

  auto loadB = [&](int k0){
    br0 = *(const float4*)(bgp + (size_t)(k0 + 0) * INTER);
    br1 = *(const float4*)(bgp + (size_t)(k0 + 1) * INTER);
  };
  auto writeB = [&](int cb){
    uint* bd = (uint*)(lds + cb + 4096);
#pragma unroll
    for (int i = 0; i < 4; i++){
      int ii = i ^ (lane & 3);
      int c = bl * 4 + ii;
      bd[c * 16 + ((Qc ^ HB(c)) << 2) + wrd] =
          pk2(((const float*)&br0)[ii], ((const float*)&br1)[ii]);
    }
  };
  auto compute = [&](int cb){
    const ushort* A = lds + cb;
    const ushort* B = lds + cb + 4096;
    bf16x8 a[4], b[2];
#pragma unroll
    for (int mf = 0; mf < 4; mf++) a[mf] = *(const bf16x8*)(A + aoff[mf]);
#pragma unroll
    for (int nf = 0; nf < 2; nf++) b[nf] = *(const bf16x8*)(B + boff[nf]);
#pragma unroll
    for (int mf = 0; mf < 4; mf++)
#pragma unroll
      for (int nf = 0; nf < 2; nf++)
        acc[mf][nf] = __builtin_amdgcn_mfma_f32_16x16x32_bf16(a[mf], b[nf], acc[mf][nf], 0, 0, 0);
  };

  // prologue
  stageA16(agp, lds + tid * 8);
  loadB(0);
  writeB(0);
  __syncthreads();

  int cb = 0;
  for (int t = 0; t < NT_GU; ++t){
    const int nb = cb ^ GUV_STRIDE;
    if (t + 1 < NT_GU){
      stageA16(agp + (t + 1) * 32, lds + nb + tid * 8);
      loadB((t + 1) * 32);
    }
    compute(cb);
    if (t + 1 < NT_GU) writeB(nb);
    __syncthreads();
    cb = nb;
  }

  // epilogue: raw GEMM result, bf16
  ushort* obuf = mat ? ubuf : gbuf;
#pragma unroll
  for (int mf = 0; mf < 4; mf++)
#pragma unroll
    for (int j = 0; j < 4; j++){
      int rl = wm * 64 + mf * 16 + ko * 4 + j;
      int gr = mt * 128 + rl;
      if (gr < cnt){
        size_t rb = (size_t)(off + gr) * INTER + n0;
#pragma unroll
        for (int nf = 0; nf < 2; nf++)
          obuf[rb + wn * 32 + nf * 16 + fr] = f2b(acc[mf][nf][j]);
      }
    }
}

// ---------------- fuse: h = silu(g) * u * wt  (in place over gbuf) ----------------
__global__ void fuse_kernel(ushort* __restrict__ gbuf, const ushort* __restrict__ ubuf,
                            const float* __restrict__ wts){
  const int s = blockIdx.x;
  const int c = threadIdx.x * 4;   // 192 threads cover 768
  const float wt = wts[s];
  size_t base = (size_t)s * INTER + c;
  uint2 gv = *(const uint2*)(gbuf + base);
  uint2 uv = *(const uint2*)(ubuf + base);
  float h[4];
  {
    float g0 = b2f((unsigned short)gv.x),        u0 = b2f((unsigned short)uv.x);
    float g1 = b2f((unsigned short)(gv.x >> 16)), u1 = b2f((unsigned short)(uv.x >> 16));
    float g2 = b2f((unsigned short)gv.y),        u2 = b2f((unsigned short)uv.y);
    float g3 = b2f((unsigned short)(gv.y >> 16)), u3 = b2f((unsigned short)(uv.y >> 16));
    h[0] = (g0 / (1.0f + __expf(-g0))) * u0 * wt;
    h[1] = (g1 / (1.0f + __expf(-g1))) * u1 * wt;
    h[2] = (g2 / (1.0f + __expf(-g2))) * u2 * wt;
    h[3] = (g3 / (1.0f + __expf(-g3))) * u3 * wt;
  }
  uint2 o; o.x = pk2(h[0], h[1]); o.y = pk2(h[2], h[3]);
  *(uint2*)(gbuf + base) = o;
}

// ---------------- down GEMM: out[tok] += h @ wd (atomic) ----------------
// BM=128, BN=256, BK=32, 24 K-steps, nt=8 (x=8: mt-pairs same XCD).
// B: wave owns 4 k-rows, lane loads 4x float4 (1KB rows); writes 4x b64
// (uint2) with chunk-XOR HB(c) + col reorder -> ~2-way banks.
#define NT_DN 24
#define DN_STRIDE 12288   // ushorts per buffer: A 4096 | B 8192
__global__ __launch_bounds__(512) void down_kernel(
    const ushort* __restrict__ hbuf, const float* __restrict__ wd,
    const int* __restrict__ rows, const int* __restrict__ counts,
    const int* __restrict__ offsets, const int* __restrict__ tlist,
    float* __restrict__ out)
{
  const int w = tlist[blockIdx.y];
  if (w < 0) return;
  const int e = w & 0xffff, mt = w >> 16;
  const int nt = blockIdx.x;   // 0..7
  const int cnt = counts[e], off = offsets[e];
  const int n0 = nt * 256;

  __shared__ __align__(16) ushort lds[2 * DN_STRIDE];  // 48 KB

  const int tid = threadIdx.x;
  const int lane = tid & 63, wv = tid >> 6;

  const int ar = tid >> 2;
  const int aq = (tid & 3) ^ (ar & 3);
  const int srow = mt * 128 + ar;
  const int slotA = off + (srow < cnt ? srow : 0);
  const ushort* agp = hbuf + (size_t)slotA * INTER + aq * 8;

  const float* bgp = wd + (size_t)e * (INTER * HID) + (size_t)(wv * 4) * HID + n0 + lane * 4;
  const int Qc = wv >> 1;
  const int wb2 = ((2 * wv) & 3) << 1;   // ushort offset of thread's 8B word-pair

  const int wm = wv >> 2, wn = wv & 3;
  const int fr = lane & 15, ko = lane >> 4;
  int aoff[4], boff[4];
#pragma unroll
  for (int mf = 0; mf < 4; mf++){
    int r = wm * 64 + mf * 16 + fr;
    aoff[mf] = r * 32 + ((ko ^ (r & 3)) << 3);
  }
#pragma unroll
  for (int nf = 0; nf < 4; nf++){
    int c = wn * 64 + nf * 16 + fr;
    boff[nf] = c * 32 + ((ko ^ HB(c)) << 3);
  }

  f32x4 acc[4][4];
#pragma unroll
  for (int i = 0; i < 4; i++)
#pragma unroll
    for (int j = 0; j < 4; j++) acc[i][j] = (f32x4)(0.0f);

  float4 br0, br1, br2, br3;

  auto loadB = [&](int k0){
    br0 = *(const float4*)(bgp + (size_t)(k0 + 0) * HID);
    br1 = *(const float4*)(bgp + (size_t)(k0 + 1) * HID);
    br2 = *(const float4*)(bgp + (size_t)(k0 + 2) * HID);
    br3 = *(const float4*)(bgp + (size_t)(k0 + 3) * HID);
  };
  auto writeB = [&](int cb){
    ushort* bd = lds + cb + 4096;
#pragma unroll
    for (int i = 0; i < 4; i++){
      int ii = i ^ (lane & 3);
      int c = lane * 4 + ii;
      uint2 p;
      p.x = pk2(((const float*)&br0)[ii], ((const float*)&br1)[ii]);
      p.y = pk2(((const float*)&br2)[ii], ((const float*)&br3)[ii]);
      *(uint2*)(bd + c * 32 + ((Qc ^ HB(c)) << 3) + wb2) = p;
    }
  };
  auto compute = [&](int cb){
    const ushort* A = lds + cb;
    const ushort* B = lds + cb + 4096;
    bf16x8 a[4], b[4];
#pragma unroll
    for (int mf = 0; mf < 4; mf++) a[mf] = *(const bf16x8*)(A + aoff[mf]);
#pragma unroll
    for (int nf = 0; nf < 4; nf++) b[nf] = *(const bf16x8*)(B + boff[nf]);
#pragma unroll
    for (int mf = 0; mf < 4; mf++)
#pragma unroll
      for (int nf = 0; nf < 4; nf++)
        acc[mf][nf] = __builtin_amdgcn_mfma_f32_16x16x32_bf16(a[mf], b[nf], acc[mf][nf], 0, 0, 0);
  };

  stageA16(agp, lds + tid * 8);
  loadB(0);
  writeB(0);
  __syncthreads();

  int cb = 0;
  for (int t = 0; t < NT_DN; ++t){
    const int nb = cb ^ DN_STRIDE;
    if (t + 1 < NT_DN){
      stageA16(agp + (t + 1) * 32, lds + nb + tid * 8);
      loadB((t + 1) * 32);
    }
    compute(cb);
    if (t + 1 < NT_DN) writeB(nb);
    __syncthreads();
    cb = nb;
  }

#pragma unroll
  for (int mf = 0; mf < 4; mf++)
#pragma unroll
    for (int j = 0; j < 4; j++){
      int rl = wm * 64 + mf * 16 + ko * 4 + j;
      int gr = mt * 128 + rl;
      if (gr < cnt){
        int tok = rows[off + gr];
        float* obase = out + (size_t)tok * HID + n0;
#pragma unroll
        for (int nf = 0; nf < 4; nf++)
          atomicAdd(obase + wn * 64 + nf * 16 + fr, acc[mf][nf][j]);
      }
    }
}

// ---------------- launch ----------------
extern "C" void kernel_launch(void* const* d_in, const int* in_sizes, int n_in,
                              void* d_out, int out_size, void* d_ws, size_t ws_size,
                              hipStream_t stream){
  const float* x  = (const float*)d_in[0];
  const float* wr = (const float*)d_in[1];
  const float* wg = (const float*)d_in[2];
  const float* wu = (const float*)d_in[3];
  const float* wd = (const float*)d_in[4];
  float* out = (float*)d_out;
  char* ws = (char*)d_ws;

  ushort* xb     = (ushort*)(ws + XB_OFF);
  ushort* gbuf   = (ushort*)(ws + GBUF_OFF);
  ushort* ubuf   = (ushort*)(ws + UBUF_OFF);
  float*  topkw  = (float*)(ws + TKW_OFF);
  int*    topki  = (int*)(ws + TKI_OFF);
  int*    rows   = (int*)(ws + ROWS_OFF);
  float*  wts    = (float*)(ws + WTS_OFF);
  int*    offs   = (int*)(ws + OFFS_OFF);
  float*  logits = (float*)(ws + LOGIT_OFF);
  int*    counts = (int*)(ws + CNT_OFF);
  int*    fill   = (int*)(ws + FILL_OFF);
  int*    tlist  = (int*)(ws + TLIST_OFF);

  hipMemsetAsync(ws + ZERO_OFF, 0, ZERO_SZ, stream);
  hipMemsetAsync(d_out, 0, (size_t)out_size * sizeof(float), stream);

  convert_x_kernel<<<2048, 256, 0, stream>>>(x, xb);
  router_gemm<<<dim3(32, 8), 256, 0, stream>>>(x, wr, logits);
  topk_kernel<<<8, 256, 0, stream>>>(logits, topkw, topki, counts);
  prefix_kernel<<<1, 64, 0, stream>>>(counts, offs, tlist);
  scatter_kernel<<<32, 256, 0, stream>>>(topki, topkw, offs, fill, rows, wts);
  guv_kernel<<<dim3(16, MAXT), 512, 0, stream>>>(xb, wg, wu, rows, counts, offs, tlist, gbuf, ubuf);
  fuse_kernel<<<NSLOT, 192, 0, stream>>>(gbuf, ubuf, wts);
  down_kernel<<<dim3(8, MAXT), 512, 0, stream>>>(gbuf, wd, rows, counts, offs, tlist, out);
}

// Round 10
// 374.429 us; speedup vs baseline: 1.7180x; 1.7180x over previous
//
#include <hip/hip_runtime.h>

#define T_TOK 2048
#define HID   2048
#define INTER 768
#define NE    32
#define NSLOT 8192   // T_TOK * TOP_K
#define MAXT  96     // max (expert, mt) tiles at BM=128

typedef short bf16x8 __attribute__((ext_vector_type(8)));
typedef float f32x4  __attribute__((ext_vector_type(4)));

__device__ __forceinline__ unsigned short f2b(float f){
  unsigned u = __builtin_bit_cast(unsigned, f);
  u += 0x7fffu + ((u >> 16) & 1u);      // RNE
  return (unsigned short)(u >> 16);
}
__device__ __forceinline__ unsigned pk2(float a, float b){
  return (unsigned)f2b(a) | ((unsigned)f2b(b) << 16);
}
__device__ __forceinline__ float b2f(unsigned short u){
  unsigned x = ((unsigned)u) << 16;
  return __builtin_bit_cast(float, x);
}

// Non-draining workgroup barrier: __syncthreads would emit s_waitcnt vmcnt(0)
// and drain the 2-deep global prefetch. We only need LDS ops retired.
__device__ __forceinline__ void wgbar(){
  asm volatile("s_waitcnt lgkmcnt(0)" ::: "memory");
  __builtin_amdgcn_s_barrier();
  __builtin_amdgcn_sched_barrier(0);
}

// ---------------- workspace layout (bytes) ----------------
#define XB_OFF    0ul           // bf16 x  [2048][2048]  = 8388608
#define GBUF_OFF  8388608ul     // bf16 g, then h in-place [8192][768] = 12582912
#define TKW_OFF   20971520ul    // f32 topk_w [2048][4]
#define TKI_OFF   21004288ul
#define ROWS_OFF  21037056ul
#define WTS_OFF   21069824ul
#define OFFS_OFF  21102592ul
#define LOGIT_OFF 21102848ul    // zeroed
#define CNT_OFF   21364992ul    // zeroed
#define FILL_OFF  21365120ul    // zeroed
#define TLIST_OFF 21365248ul
#define UBUF_OFF  21365760ul    // bf16 u [8192][768] = 12582912 (ends ~34 MB)
#define ZERO_OFF  21102848ul
#define ZERO_SZ   (262144ul + 128ul + 128ul)

// ---------------- x fp32 -> bf16 ----------------
__global__ void convert_x_kernel(const float* __restrict__ x, ushort* __restrict__ xb){
  int i = (blockIdx.x * 256 + threadIdx.x) * 8;
  float4 a = *(const float4*)(x + i);
  float4 b = *(const float4*)(x + i + 4);
  uint4 o;
  o.x = pk2(a.x, a.y);
  o.y = pk2(a.z, a.w);
  o.z = pk2(b.x, b.y);
  o.w = pk2(b.z, b.w);
  *(uint4*)(xb + i) = o;
}

// ---------------- router logits (fp32 GEMM, split-K atomic) ----------------
__global__ void router_gemm(const float* __restrict__ x, const float* __restrict__ wr,
                            float* __restrict__ logits){
  const int tt = blockIdx.x;
  const int kb = blockIdx.y;
  __shared__ float xs[64 * 64];
  __shared__ float wsm[64 * 32];
  const int tid = threadIdx.x;
  const int r = tid >> 5, e = tid & 31;
  float acc[8];
#pragma unroll
  for (int i = 0; i < 8; i++) acc[i] = 0.0f;

  for (int sub = 0; sub < 4; ++sub){
    const int k0 = kb * 256 + sub * 64;
    __syncthreads();
#pragma unroll
    for (int j = 0; j < 4; j++){
      int f4 = tid + j * 256;
      int row = f4 >> 4, c4 = f4 & 15;
      float4 v = *(const float4*)(x + (size_t)(tt * 64 + row) * HID + k0 + c4 * 4);
      *(float4*)(xs + row * 64 + c4 * 4) = v;
    }
#pragma unroll
    for (int j = 0; j < 2; j++){
      int f4 = tid + j * 256;
      int row = f4 >> 3, c4 = f4 & 7;
      float4 v = *(const float4*)(wr + (size_t)(k0 + row) * NE + c4 * 4);
      *(float4*)(wsm + row * NE + c4 * 4) = v;
    }
    __syncthreads();
    for (int kk = 0; kk < 64; kk++){
      float wv = wsm[kk * NE + e];
#pragma unroll
      for (int i = 0; i < 8; i++) acc[i] += xs[(r + i * 8) * 64 + kk] * wv;
    }
  }
#pragma unroll
  for (int i = 0; i < 8; i++)
    atomicAdd(&logits[(size_t)(tt * 64 + r + i * 8) * NE + e], acc[i]);
}

// ---------------- softmax + top-4 + renorm + counts ----------------
__global__ void topk_kernel(const float* __restrict__ logits, float* __restrict__ topk_w,
                            int* __restrict__ topk_i, int* __restrict__ counts){
  int t = blockIdx.x * blockDim.x + threadIdx.x;
  if (t >= T_TOK) return;
  float l[32];
  const float4* lp = (const float4*)(logits + (size_t)t * NE);
#pragma unroll
  for (int i = 0; i < 8; i++){
    float4 v = lp[i];
    l[i*4+0] = v.x; l[i*4+1] = v.y; l[i*4+2] = v.z; l[i*4+3] = v.w;
  }
  float m = l[0];
#pragma unroll
  for (int i = 1; i < 32; i++) m = fmaxf(m, l[i]);
#pragma unroll
  for (int i = 0; i < 32; i++) l[i] = __expf(l[i] - m);
  float wsel[4]; int isel[4];
#pragma unroll
  for (int k = 0; k < 4; k++){
    float best = l[0]; int bi = 0;
#pragma unroll
    for (int i = 1; i < 32; i++){ if (l[i] > best){ best = l[i]; bi = i; } }
    wsel[k] = best; isel[k] = bi; l[bi] = -1.0f;
  }
  float s4 = wsel[0] + wsel[1] + wsel[2] + wsel[3];
  float inv = 1.0f / s4;
#pragma unroll
  for (int k = 0; k < 4; k++){
    topk_w[t * 4 + k] = wsel[k] * inv;
    topk_i[t * 4 + k] = isel[k];
    atomicAdd(&counts[isel[k]], 1);
  }
}

__global__ void prefix_kernel(const int* __restrict__ counts, int* __restrict__ offsets,
                              int* __restrict__ tlist){
  if (threadIdx.x == 0){
    int a = 0; offsets[0] = 0; int nt_ = 0;
    for (int e = 0; e < NE; e++){
      int c = counts[e];
      for (int m = 0; m * 128 < c && nt_ < MAXT; m++) tlist[nt_++] = e | (m << 16);
      a += c; offsets[e + 1] = a;
    }
    for (; nt_ < MAXT; nt_++) tlist[nt_] = -1;
  }
}

__global__ void scatter_kernel(const int* __restrict__ topk_i, const float* __restrict__ topk_w,
                               const int* __restrict__ offsets, int* __restrict__ fill,
                               int* __restrict__ rows, float* __restrict__ wts){
  int gid = blockIdx.x * 256 + threadIdx.x;
  int t = gid >> 2;
  int e = topk_i[gid];
  int pos = atomicAdd(&fill[e], 1);
  int s = offsets[e] + pos;
  rows[s] = t;
  wts[s] = topk_w[gid];
}

// ---------------- gate/up GEMM (split matrices) ----------------
// BM=128, BN=256, BK=32, 512 thr (8 waves, 2m x 4n, 16 MFMA/step/wave).
// LDS stride-40 ushorts (r5-measured ZERO bank conflicts; r9 lesson: 64B
// col stride cancels lane bits -> unavoidable conflicts). B global loads:
// lane l owns cols {l, l+64, l+128, l+192} -> per-instr 256B contiguous
// segments, LDS write banks = 20*lane + 2*wv (8-bank spread, r5 pattern).
// 2-deep prefetch with NON-DRAINING raw s_barrier (one per tile): loads for
// tile t+2 issued a full tile before their LDS write -> HBM latency hidden.
#define NT_GU 64
#define A_USH 5120        // 128 rows * 40
#define BUF_USH 15360     // A 5120 + B 256*40
__global__ __launch_bounds__(512, 2) void guv_kernel(
    const ushort* __restrict__ xb, const float* __restrict__ wg,
    const float* __restrict__ wu, const int* __restrict__ rows,
    const int* __restrict__ counts, const int* __restrict__ offsets,
    const int* __restrict__ tlist, ushort* __restrict__ gbuf,
    ushort* __restrict__ ubuf)
{
  const int w = tlist[blockIdx.y];
  if (w < 0) return;
  const int e = w & 0xffff, mt = w >> 16;
  const int mat = blockIdx.x & 1, nt = blockIdx.x >> 1;   // nt 0..2
  const int cnt = counts[e], off = offsets[e];
  const int n0 = nt * 256;

  __shared__ __align__(16) ushort lds[2 * BUF_USH];  // 61440 B

  const int tid = threadIdx.x;
  const int lane = tid & 63, wv = tid >> 6;

  // A staging (regs; padded stride incompatible with global_load_lds)
  const int ar = tid >> 2, ablk = tid & 3;
  const int srow = mt * 128 + ar;
  const int tokA = rows[off + (srow < cnt ? srow : 0)];
  const ushort* agp = xb + (size_t)tokA * HID + ablk * 8;
  const int adst = ar * 40 + ablk * 8;

  // B staging: wave wv -> k-rows 4wv..4wv+3; lane l -> cols l+64i
  const float* wsel = mat ? wu : wg;
  const float* bgp = wsel + (size_t)e * (HID * INTER) + (size_t)(wv * 4) * INTER + n0 + lane;
  const int bdst = A_USH + lane * 40 + wv * 4;   // + i*2560 per col-group

  // compute roles: 2m x 4n
  const int wm = wv >> 2, wn = wv & 3;
  const int fr = lane & 15, ko = lane >> 4;
  int aoff[4], boff[4];
#pragma unroll
  for (int mf = 0; mf < 4; mf++) aoff[mf] = (wm * 64 + mf * 16 + fr) * 40 + ko * 8;
#pragma unroll
  for (int nf = 0; nf < 4; nf++) boff[nf] = A_USH + (wn * 64 + nf * 16 + fr) * 40 + ko * 8;

  f32x4 acc[4][4];
#pragma unroll
  for (int i = 0; i < 4; i++)
#pragma unroll
    for (int j = 0; j < 4; j++) acc[i][j] = (f32x4)(0.0f);

  uint4 a0, a1; uint2 b0[4], b1[4];

  auto loadSet = [&](int k0, uint4 &aa, uint2 *bb){
    aa = *(const uint4*)(agp + k0);
#pragma unroll
    for (int i = 0; i < 4; i++){
      float v0 = bgp[(size_t)(k0 + 0) * INTER + i * 64];
      float v1 = bgp[(size_t)(k0 + 1) * INTER + i * 64];
      float v2 = bgp[(size_t)(k0 + 2) * INTER + i * 64];
      float v3 = bgp[(size_t)(k0 + 3) * INTER + i * 64];
      bb[i].x = pk2(v0, v1); bb[i].y = pk2(v2, v3);
    }
  };
  auto writeSet = [&](int base, const uint4 &aa, const uint2 *bb){
    *(uint4*)(lds + base + adst) = aa;
#pragma unroll
    for (int i = 0; i < 4; i++)
      *(uint2*)(lds + base + bdst + i * 2560) = bb[i];
  };
  auto compute = [&](int base){
    bf16x8 a[4], b[4];
#pragma unroll
    for (int mf = 0; mf < 4; mf++) a[mf] = *(const bf16x8*)(lds + base + aoff[mf]);
#pragma unroll
    for (int nf = 0; nf < 4; nf++) b[nf] = *(const bf16x8*)(lds + base + boff[nf]);
#pragma unroll
    for (int mf = 0; mf < 4; mf++)
#pragma unroll
      for (int nf = 0; nf < 4; nf++)
        acc[mf][nf] = __builtin_amdgcn_mfma_f32_16x16x32_bf16(a[mf], b[nf], acc[mf][nf], 0, 0, 0);
  };

  // prologue: tiles 0,1 loaded; tile 0 -> buf0
  loadSet(0, a0, b0);
  loadSet(32, a1, b1);
  writeSet(0, a0, b0);
  wgbar();

  for (int t = 0; t < NT_GU; t += 2){
    if (t + 2 < NT_GU) loadSet((t + 2) * 32, a0, b0);
    compute(0);
    writeSet(BUF_USH, a1, b1);
    wgbar();
    if (t + 3 < NT_GU) loadSet((t + 3) * 32, a1, b1);
    compute(BUF_USH);
    if (t + 2 < NT_GU){ writeSet(0, a0, b0); wgbar(); }
  }

  // epilogue: raw GEMM result, bf16. 4 nf x 16 lanes = 128B/wave-row
  // (r9 lesson: partial-line epilogues cause massive write amplification).
  ushort* obuf = mat ? ubuf : gbuf;
#pragma unroll
  for (int mf = 0; mf < 4; mf++)
#pragma unroll
    for (int j = 0; j < 4; j++){
      int rl = wm * 64 + mf * 16 + ko * 4 + j;
      int gr = mt * 128 + rl;
      if (gr < cnt){
        size_t rb = (size_t)(off + gr) * INTER + n0;
#pragma unroll
        for (int nf = 0; nf < 4; nf++)
          obuf[rb + wn * 64 + nf * 16 + fr] = f2b(acc[mf][nf][j]);
      }
    }
}

// ---------------- fuse: h = silu(g) * u * wt  (in place over gbuf) ----------------
__global__ void fuse_kernel(ushort* __restrict__ gbuf, const ushort* __restrict__ ubuf,
                            const float* __restrict__ wts){
  const int s = blockIdx.x;
  const int c = threadIdx.x * 4;   // 192 threads cover 768
  const float wt = wts[s];
  size_t base = (size_t)s * INTER + c;
  uint2 gv = *(const uint2*)(gbuf + base);
  uint2 uv = *(const uint2*)(ubuf + base);
  float h[4];
  {
    float g0 = b2f((unsigned short)gv.x),        u0 = b2f((unsigned short)uv.x);
    float g1 = b2f((unsigned short)(gv.x >> 16)), u1 = b2f((unsigned short)(uv.x >> 16));
    float g2 = b2f((unsigned short)gv.y),        u2 = b2f((unsigned short)uv.y);
    float g3 = b2f((unsigned short)(gv.y >> 16)), u3 = b2f((unsigned short)(uv.y >> 16));
    h[0] = (g0 / (1.0f + __expf(-g0))) * u0 * wt;
    h[1] = (g1 / (1.0f + __expf(-g1))) * u1 * wt;
    h[2] = (g2 / (1.0f + __expf(-g2))) * u2 * wt;
    h[3] = (g3 / (1.0f + __expf(-g3))) * u3 * wt;
  }
  uint2 o; o.x = pk2(h[0], h[1]); o.y = pk2(h[2], h[3]);
  *(uint2*)(gbuf + base) = o;
}

// ---------------- down GEMM: out[tok] += h @ wd (atomic) ----------------
// Same template: BM=128, BN=256, BK=32, 24 K-steps, nt=8.
#define NT_DN 24
__global__ __launch_bounds__(512, 2) void down_kernel(
    const ushort* __restrict__ hbuf, const float* __restrict__ wd,
    const int* __restrict__ rows, const int* __restrict__ counts,
    const int* __restrict__ offsets, const int* __restrict__ tlist,
    float* __restrict__ out)
{
  const int w = tlist[blockIdx.y];
  if (w < 0) return;
  const int e = w & 0xffff, mt = w >> 16;
  const int nt = blockIdx.x;   // 0..7
  const int cnt = counts[e], off = offsets[e];
  const int n0 = nt * 256;

  __shared__ __align__(16) ushort lds[2 * BUF_USH];  // 61440 B

  const int tid = threadIdx.x;
  const int lane = tid & 63, wv = tid >> 6;

  const int ar = tid >> 2, ablk = tid & 3;
  const int srow = mt * 128 + ar;
  const int slotA = off + (srow < cnt ? srow : 0);
  const ushort* agp = hbuf + (size_t)slotA * INTER + ablk * 8;
  const int adst = ar * 40 + ablk * 8;

  const float* bgp = wd + (size_t)e * (INTER * HID) + (size_t)(wv * 4) * HID + n0 + lane;
  const int bdst = A_USH + lane * 40 + wv * 4;

  const int wm = wv >> 2, wn = wv & 3;
  const int fr = lane & 15, ko = lane >> 4;
  int aoff[4], boff[4];
#pragma unroll
  for (int mf = 0; mf < 4; mf++) aoff[mf] = (wm * 64 + mf * 16 + fr) * 40 + ko * 8;
#pragma unroll
  for (int nf = 0; nf < 4; nf++) boff[nf] = A_USH + (wn * 64 + nf * 16 + fr) * 40 + ko * 8;

  f32x4 acc[4][4];
#pragma unroll
  for (int i = 0; i < 4; i++)
#pragma unroll
    for (int j = 0; j < 4; j++) acc[i][j] = (f32x4)(0.0f);

  uint4 a0, a1; uint2 b0[4], b1[4];

  auto loadSet = [&](int k0, uint4 &aa, uint2 *bb){
    aa = *(const uint4*)(agp + k0);
#pragma unroll
    for (int i = 0; i < 4; i++){
      float v0 = bgp[(size_t)(k0 + 0) * HID + i * 64];
      float v1 = bgp[(size_t)(k0 + 1) * HID + i * 64];
      float v2 = bgp[(size_t)(k0 + 2) * HID + i * 64];
      float v3 = bgp[(size_t)(k0 + 3) * HID + i * 64];
      bb[i].x = pk2(v0, v1); bb[i].y = pk2(v2, v3);
    }
  };
  auto writeSet = [&](int base, const uint4 &aa, const uint2 *bb){
    *(uint4*)(lds + base + adst) = aa;
#pragma unroll
    for (int i = 0; i < 4; i++)
      *(uint2*)(lds + base + bdst + i * 2560) = bb[i];
  };
  auto compute = [&](int base){
    bf16x8 a[4], b[4];
#pragma unroll
    for (int mf = 0; mf < 4; mf++) a[mf] = *(const bf16x8*)(lds + base + aoff[mf]);
#pragma unroll
    for (int nf = 0; nf < 4; nf++) b[nf] = *(const bf16x8*)(lds + base + boff[nf]);
#pragma unroll
    for (int mf = 0; mf < 4; mf++)
#pragma unroll
      for (int nf = 0; nf < 4; nf++)
        acc[mf][nf] = __builtin_amdgcn_mfma_f32_16x16x32_bf16(a[mf], b[nf], acc[mf][nf], 0, 0, 0);
  };

  loadSet(0, a0, b0);
  loadSet(32, a1, b1);
  writeSet(0, a0, b0);
  wgbar();

  for (int t = 0; t < NT_DN; t += 2){
    if (t + 2 < NT_DN) loadSet((t + 2) * 32, a0, b0);
    compute(0);
    writeSet(BUF_USH, a1, b1);
    wgbar();
    if (t + 3 < NT_DN) loadSet((t + 3) * 32, a1, b1);
    compute(BUF_USH);
    if (t + 2 < NT_DN){ writeSet(0, a0, b0); wgbar(); }
  }

#pragma unroll
  for (int mf = 0; mf < 4; mf++)
#pragma unroll
    for (int j = 0; j < 4; j++){
      int rl = wm * 64 + mf * 16 + ko * 4 + j;
      int gr = mt * 128 + rl;
      if (gr < cnt){
        int tok = rows[off + gr];
        float* obase = out + (size_t)tok * HID + n0;
#pragma unroll
        for (int nf = 0; nf < 4; nf++)
          atomicAdd(obase + wn * 64 + nf * 16 + fr, acc[mf][nf][j]);
      }
    }
}

// ---------------- launch ----------------
extern "C" void kernel_launch(void* const* d_in, const int* in_sizes, int n_in,
                              void* d_out, int out_size, void* d_ws, size_t ws_size,
                              hipStream_t stream){
  const float* x  = (const float*)d_in[0];
  const float* wr = (const float*)d_in[1];
  const float* wg = (const float*)d_in[2];
  const float* wu = (const float*)d_in[3];
  const float* wd = (const float*)d_in[4];
  float* out = (float*)d_out;
  char* ws = (char*)d_ws;

  ushort* xb     = (ushort*)(ws + XB_OFF);
  ushort* gbuf   = (ushort*)(ws + GBUF_OFF);
  ushort* ubuf   = (ushort*)(ws + UBUF_OFF);
  float*  topkw  = (float*)(ws + TKW_OFF);
  int*    topki  = (int*)(ws + TKI_OFF);
  int*    rows   = (int*)(ws + ROWS_OFF);
  float*  wts    = (float*)(ws + WTS_OFF);
  int*    offs   = (int*)(ws + OFFS_OFF);
  float*  logits = (float*)(ws + LOGIT_OFF);
  int*    counts = (int*)(ws + CNT_OFF);
  int*    fill   = (int*)(ws + FILL_OFF);
  int*    tlist  = (int*)(ws + TLIST_OFF);

  hipMemsetAsync(ws + ZERO_OFF, 0, ZERO_SZ, stream);
  hipMemsetAsync(d_out, 0, (size_t)out_size * sizeof(float), stream);

  convert_x_kernel<<<2048, 256, 0, stream>>>(x, xb);
  router_gemm<<<dim3(32, 8), 256, 0, stream>>>(x, wr, logits);
  topk_kernel<<<8, 256, 0, stream>>>(logits, topkw, topki, counts);
  prefix_kernel<<<1, 64, 0, stream>>>(counts, offs, tlist);
  scatter_kernel<<<32, 256, 0, stream>>>(topki, topkw, offs, fill, rows, wts);
  guv_kernel<<<dim3(6, MAXT), 512, 0, stream>>>(xb, wg, wu, rows, counts, offs, tlist, gbuf, ubuf);
  fuse_kernel<<<NSLOT, 192, 0, stream>>>(gbuf, ubuf, wts);
  down_kernel<<<dim3(8, MAXT), 512, 0, stream>>>(gbuf, wd, rows, counts, offs, tlist, out);
}